// Round 14
// baseline (40.934 us; speedup 1.0000x reference)
//
#include <hip/hip_runtime.h>

#define B_  4
#define NQ_ 256
#define NK_ 512
#define H_  256
#define PADE 516   // float4s per E row (512 + 4 pad): stride 8256B, not 8KB

// 2*log2(e): exp2(x*TWO_LOG2E) = e^{2x}
#define TWO_LOG2E 2.8853900817779268f

// Both GEMMs in one launch, 32x64 tiles, 256 threads, 8 outputs/thread
// (4m x 2n), register-double-buffered staging. 384 blocks = 1.5 blocks/CU
// (was 192 = 0.75 -- gemm was pure latency exposure at 16us vs 2.6us FLOP
// floor). Epilogues store EXP of the transforms:
//   blocks [0,256):  E[b][o>>2][k][o&3] = e^{2*kt[b][o][k]}   (padded rows)
//   blocks [256,384): F[b][q][o]        = e^{2*qt[b][q][o]}
// tanh(a+b) = 1 - 2/(1 + e^{2a}e^{2b}) is EXACT; d >= 1 always.
__global__ __launch_bounds__(256)
void gemm_fused(const float* __restrict__ xq, const float* __restrict__ xk,
                const float* __restrict__ w1, const float* __restrict__ w2,
                float* __restrict__ Ebuf,    // [B][64][PADE*4] floats
                float* __restrict__ Fbuf)    // [B][NQ][H]
{
    constexpr int BK = 32;
    const float* A; const float* Bm;
    int m0, n0, bz; bool iskt;
    {
        int id = blockIdx.x;
        if (id < 256) {                      // kt: M=H(o) 8 tiles, N=NK(k) 8 tiles
            iskt = true;
            bz = id >> 6; int t = id & 63;
            m0 = (t >> 3) * 32; n0 = (t & 7) * 64;
            A = w1; Bm = xk + (long)bz * NK_ * H_;
        } else {                             // qt: M=NQ(q) 8 tiles, N=H(o) 4 tiles
            iskt = false;
            id -= 256;
            bz = id >> 5; int t = id & 31;
            m0 = (t >> 2) * 32; n0 = (t & 3) * 64;
            A = xq + (long)bz * NQ_ * H_; Bm = w2;
        }
    }
    const int lda = H_, ldb = H_;

    __shared__ float As[BK][36];
    __shared__ float Bs[BK][68];

    const int tid  = threadIdx.x;
    const int arow = tid >> 3, ak = (tid & 7) * 4;   // 32 rows x 32 k, 1 float4
    const int brow = tid >> 2, bk = (tid & 3) * 8;   // 64 rows x 32 k, 2 float4
    const int tm = (tid >> 5) * 4;       // 0..28
    const int tn = (tid & 31) * 2;       // 0..62

    float acc[4][2] = {};

    float4 a_r  = *(const float4*)&A [(long)(m0 + arow) * lda + ak];
    float4 b0_r = *(const float4*)&Bm[(long)(n0 + brow) * ldb + bk];
    float4 b1_r = *(const float4*)&Bm[(long)(n0 + brow) * ldb + bk + 4];
    float4 a_n = a_r, b0_n = b0_r, b1_n = b1_r;

    for (int kt = 0; kt < H_; kt += BK) {
        __syncthreads();
        As[ak+0][arow]=a_r.x; As[ak+1][arow]=a_r.y; As[ak+2][arow]=a_r.z; As[ak+3][arow]=a_r.w;
        Bs[bk+0][brow]=b0_r.x; Bs[bk+1][brow]=b0_r.y; Bs[bk+2][brow]=b0_r.z; Bs[bk+3][brow]=b0_r.w;
        Bs[bk+4][brow]=b1_r.x; Bs[bk+5][brow]=b1_r.y; Bs[bk+6][brow]=b1_r.z; Bs[bk+7][brow]=b1_r.w;
        if (kt + BK < H_) {
            a_n  = *(const float4*)&A [(long)(m0 + arow) * lda + kt + BK + ak];
            b0_n = *(const float4*)&Bm[(long)(n0 + brow) * ldb + kt + BK + bk];
            b1_n = *(const float4*)&Bm[(long)(n0 + brow) * ldb + kt + BK + bk + 4];
        }
        __syncthreads();
        #pragma unroll
        for (int kk = 0; kk < BK; ++kk) {
            float4 av = *(const float4*)&As[kk][tm];
            float2 bv = *(const float2*)&Bs[kk][tn];
            float am[4] = {av.x, av.y, av.z, av.w};
            #pragma unroll
            for (int i = 0; i < 4; ++i) {
                acc[i][0] = fmaf(am[i], bv.x, acc[i][0]);
                acc[i][1] = fmaf(am[i], bv.y, acc[i][1]);
            }
        }
        a_r = a_n; b0_r = b0_n; b1_r = b1_n;
    }

    if (iskt) {
        // rows o = m0+tm..+3 consecutive -> one float4 per output column k
        float4* cb = (float4*)Ebuf + ((long)bz * 64 + ((m0 + tm) >> 2)) * PADE;
        #pragma unroll
        for (int j = 0; j < 2; ++j) {
            float4 e4 = { __builtin_amdgcn_exp2f(acc[0][j] * TWO_LOG2E),
                          __builtin_amdgcn_exp2f(acc[1][j] * TWO_LOG2E),
                          __builtin_amdgcn_exp2f(acc[2][j] * TWO_LOG2E),
                          __builtin_amdgcn_exp2f(acc[3][j] * TWO_LOG2E) };
            cb[n0 + tn + j] = e4;
        }
    } else {
        #pragma unroll
        for (int i = 0; i < 4; ++i) {
            float2 f2v = { __builtin_amdgcn_exp2f(acc[i][0] * TWO_LOG2E),
                           __builtin_amdgcn_exp2f(acc[i][1] * TWO_LOG2E) };
            *(float2*)&Fbuf[((long)bz * NQ_ + m0 + tm + i) * H_ + n0 + tn] = f2v;
        }
    }
}

// One block per (b, 4 q-rows), 512 threads = one per k.
// prod[q,k] = -2 * sum_h v[h] / (1 + E[h,k]*F[q,h])   (Sum v cancels in LSM)
// F rows (4, contiguous) and v are WAVE-UNIFORM -> s_load into SGPRs.
// QPB 2->4 halves the E L2 stream (268->134 MB), the largest remaining term.
// E is the only vector stream: 1 float4 per 4h, 8-deep register prefetch.
__global__ __launch_bounds__(512, 2)
void attn_main(const float4* __restrict__ E4,   // [B][64][PADE]
               const float* __restrict__ Fbuf,  // [B][NQ][H]
               const float* __restrict__ v,     // [H]
               float* __restrict__ out)         // [B][NQ][NK]
{
    const int k = threadIdx.x, b = blockIdx.y, q0 = blockIdx.x * 4;

    const float4* kp  = E4 + (long)b * 64 * PADE + k;
    const float4* Fb  = (const float4*)(Fbuf + ((long)b * NQ_ + q0) * H_);
    const float4* v4p = (const float4*)v;

    float T0 = 0.f, T1 = 0.f, T2 = 0.f, T3 = 0.f;

    // 8-deep E prefetch: A = current group, B = next, C = landing
    float4 ka0 = kp[0*PADE], ka1 = kp[1*PADE], ka2 = kp[2*PADE], ka3 = kp[3*PADE];
    float4 kb0 = kp[4*PADE], kb1 = kp[5*PADE], kb2 = kp[6*PADE], kb3 = kp[7*PADE];
    float4 kc0 = ka0, kc1 = ka1, kc2 = ka2, kc3 = ka3;

#define QTERM(T, EV, FQ, VV)                                                  \
    {                                                                         \
        float d0 = fmaf(EV.x, FQ.x, 1.f), d1 = fmaf(EV.y, FQ.y, 1.f);         \
        float d2 = fmaf(EV.z, FQ.z, 1.f), d3 = fmaf(EV.w, FQ.w, 1.f);         \
        float D01 = d0 * d1, D23 = d2 * d3;                                   \
        float N01 = fmaf(VV.x, d1, VV.y * d0);                                \
        float N23 = fmaf(VV.z, d3, VV.w * d2);                                \
        float N   = fmaf(N01, D23, N23 * D01);                                \
        T = fmaf(N, __builtin_amdgcn_rcpf(D01 * D23), T);                     \
    }
#define PROC4(EV, HC)                                                         \
    {                                                                         \
        float4 vv = v4p[HC];             /* uniform -> s_load_dwordx4 */      \
        float4 f0 = Fb[HC];                                                   \
        float4 f1 = Fb[64 + (HC)];                                            \
        float4 f2 = Fb[128 + (HC)];                                           \
        float4 f3 = Fb[192 + (HC)];                                           \
        QTERM(T0, EV, f0, vv)                                                 \
        QTERM(T1, EV, f1, vv)                                                 \
        QTERM(T2, EV, f2, vv)                                                 \
        QTERM(T3, EV, f3, vv)                                                 \
    }

    for (int g = 0; g < 64; g += 4) {
        if (g + 8 < 64) {          // land rows g+8..g+11 in C
            kc0 = kp[(long)(g +  8) * PADE];
            kc1 = kp[(long)(g +  9) * PADE];
            kc2 = kp[(long)(g + 10) * PADE];
            kc3 = kp[(long)(g + 11) * PADE];
        }
        PROC4(ka0, g + 0)
        PROC4(ka1, g + 1)
        PROC4(ka2, g + 2)
        PROC4(ka3, g + 3)
        ka0 = kb0; ka1 = kb1; ka2 = kb2; ka3 = kb3;
        kb0 = kc0; kb1 = kc1; kb2 = kc2; kb3 = kc3;
    }
#undef PROC4
#undef QTERM

    float val[4] = { -2.f * T0, -2.f * T1, -2.f * T2, -2.f * T3 };

    // ---- log-softmax over k, no max pass (|val| <= 2*sum|v| ~ 16, safe) ----
    __shared__ float red[8][4];
    const int lane = k & 63, wv = k >> 6;

    #pragma unroll
    for (int j = 0; j < 4; ++j) {
        float e = __builtin_amdgcn_exp2f(val[j] * 1.4426950408889634f);
        #pragma unroll
        for (int o = 32; o; o >>= 1) e += __shfl_xor(e, o, 64);
        if (lane == 0) red[wv][j] = e;
    }
    __syncthreads();
    #pragma unroll
    for (int j = 0; j < 4; ++j) {
        float s = 0.f;
        #pragma unroll
        for (int w = 0; w < 8; ++w) s += red[w][j];
        float l = __builtin_amdgcn_logf(s) * 0.6931471805599453f;  // ln(s)
        out[((long)b * NQ_ + q0 + j) * NK_ + k] = val[j] - l;
    }
}

extern "C" void kernel_launch(void* const* d_in, const int* in_sizes, int n_in,
                              void* d_out, int out_size, void* d_ws, size_t ws_size,
                              hipStream_t stream)
{
    const float* xq = (const float*)d_in[0];  // (4,256,256)
    const float* xk = (const float*)d_in[1];  // (4,512,256)
    const float* w1 = (const float*)d_in[2];  // (256,256) out,in
    const float* w2 = (const float*)d_in[3];  // (256,256)
    const float* v  = (const float*)d_in[4];  // (1,256)
    float* out = (float*)d_out;

    float* Ebuf = (float*)d_ws;                             // [4][64][516*4] ~2.1 MB
    float* Fbuf = Ebuf + (size_t)B_ * 64 * PADE * 4;        // [4][256][256]  = 1 MB

    gemm_fused<<<dim3(384), 256, 0, stream>>>(xq, xk, w1, w2, Ebuf, Fbuf);
    attn_main<<<dim3(NQ_ / 4, B_), 512, 0, stream>>>(
        (const float4*)Ebuf, Fbuf, v, out);
}